// Round 6
// baseline (244.190 us; speedup 1.0000x reference)
//
#include <hip/hip_runtime.h>
#include <math.h>

// out[b,s,d] = x[b,s,d] + enc(s,d)
// enc(s,d) = even(d) ? sin(s * 10000^(-d/D)) : cos(s * 10000^(-d/D))
// x: fp32 [B=8, S=4096, D=1024]. Memory-bound streaming add.
//
// v6: inline-asm guaranteed 8-deep read pipeline.
// History: v1 81us / v3 ~86us / v4 92us / v5 88us -- ALL plateau at
// 2.3-2.9 TB/s with VGPR_Count 24-32. 8 in-flight float4 need 32 data VGPRs,
// so VGPR=32 proves the compiler re-serialized the loads in every variant
// (sched_barrier(0) included: RA + hazard pass undid it). Reads need latency
// hiding (fillBuffer write-only hits 6.6 TB/s at 9% occupancy; reads stuck).
// Fix: 8x global_load_dwordx4 as asm volatile (cannot be reordered/renarrowed;
// forces 8 live f32x4 quads), then per-k `s_waitcnt vmcnt(7)` with a "+v" tie
// so each add data-depends on its waitcnt (rule-#18-safe; cannot hoist).
// vmcnt FIFO: before use of load k, issued = 8 loads + k stores ->
// outstanding<=7 <=> loads 0..k retired; never blocks on a store.
//
// Mapping: t in [0,2^20): col=t&255, s=t>>8 (same for all 8 batches!) ->
// ONE enc f32x4 per thread, reused 8x. Batch plane stride = 16 MiB.

#define S_LEN 4096
#define D_LEN 1024

typedef float f32x4 __attribute__((ext_vector_type(4)));

__global__ __launch_bounds__(256) void pe_add_kernel(
    const float* __restrict__ x, float* __restrict__ out, int B) {
    const int t = blockIdx.x * 256 + threadIdx.x;   // 0..1048575

    const float c = -9.210340371976184f / (float)D_LEN;  // -ln(10000)/1024

    if (B == 8) {
        const int col = t & 255;        // f4 column in row
        const int s   = t >> 8;         // row 0..4095 (same for every batch)
        const int d0  = col << 2;
        const float sf = (float)s;

        // one enc vector, reused for all 8 batches
        f32x4 e;
        e.x = sinf(sf * expf((float)(d0 + 0) * c));
        e.y = cosf(sf * expf((float)(d0 + 1) * c));
        e.z = sinf(sf * expf((float)(d0 + 2) * c));
        e.w = cosf(sf * expf((float)(d0 + 3) * c));

        // per-lane byte offset within one batch plane (max 16 MiB, fits 32b)
        const unsigned int voff = (unsigned int)t << 4;

        // --- 1) issue 8 independent loads; asm volatile = issue order fixed,
        //        8 distinct quad outputs = 32 data VGPRs forced live ---
        f32x4 v0, v1, v2, v3, v4, v5, v6, v7;
        #define LOADK(vk, k)                                                  \
            asm volatile("global_load_dwordx4 %0, %1, %2"                     \
                         : "=v"(vk)                                           \
                         : "v"(voff), "s"(x + ((size_t)(k) << 22))            \
                         : "memory")
        LOADK(v0, 0); LOADK(v1, 1); LOADK(v2, 2); LOADK(v3, 3);
        LOADK(v4, 4); LOADK(v5, 5); LOADK(v6, 6); LOADK(v7, 7);
        #undef LOADK

        // --- 2) retire loads in FIFO order; vmcnt(7) is exact for every k ---
        f32x4* o = (f32x4*)out;
        #define STEPK(vk, k)                                                  \
            asm volatile("s_waitcnt vmcnt(7)" : "+v"(vk) :: "memory");        \
            vk += e;                                                          \
            o[((size_t)(k) << 20) + (size_t)t] = vk
        STEPK(v0, 0); STEPK(v1, 1); STEPK(v2, 2); STEPK(v3, 3);
        STEPK(v4, 4); STEPK(v5, 5); STEPK(v6, 6); STEPK(v7, 7);
        #undef STEPK
    } else {
        // --- generic fallback (not perf-critical) ---
        const size_t nf4 = (size_t)B * S_LEN * (D_LEN / 4);
        for (size_t i = t; i < nf4; i += (size_t)4096 * 256) {
            const int col = (int)(i & 255);
            const int srow = (int)((i >> 8) & (S_LEN - 1));
            const int d0 = col << 2;
            const float sf = (float)srow;
            f32x4 e;
            e.x = sinf(sf * expf((float)(d0 + 0) * c));
            e.y = cosf(sf * expf((float)(d0 + 1) * c));
            e.z = sinf(sf * expf((float)(d0 + 2) * c));
            e.w = cosf(sf * expf((float)(d0 + 3) * c));
            f32x4 v = ((const f32x4*)x)[i];
            v += e;
            ((f32x4*)out)[i] = v;
        }
    }
}

extern "C" void kernel_launch(void* const* d_in, const int* in_sizes, int n_in,
                              void* d_out, int out_size, void* d_ws, size_t ws_size,
                              hipStream_t stream) {
    const float* x = (const float*)d_in[0];
    float* out = (float*)d_out;
    const int B = in_sizes[0] / (S_LEN * D_LEN);  // = 8

    dim3 grid(4096);   // 2^20 threads: one f4-column x row per thread, 8 batches deep
    dim3 block(256);
    pe_add_kernel<<<grid, block, 0, stream>>>(x, out, B);
}